// Round 6
// baseline (228.487 us; speedup 1.0000x reference)
//
#include <hip/hip_runtime.h>

// ExtractTensorPatches: x (16,3,512,512) f32, window 16x16, stride 8x8, pad 0.
// out (16, 63*63, 3, 16, 16) f32.
//
// Block = (b, c, ph): stage 16 input rows (contiguous 32 KB) into LDS, emit
// 63 patches. R6 changes vs R5 (theory: write-path efficiency):
//  - plain stores, NOT nontemporal (fills hit 6.5 TB/s through L2; nt may
//    defeat per-XCD L2 write aggregation)
//  - each wave owns a contiguous run of 16 patches -> monotone per-wave
//    write stream (1 KB chunks at 3 KB stride) instead of 12 KB hops
//  - emit fully unrolled (16 independent ds_read_b128 batched before stores)

#define BB 16
#define CC 3
#define HH 512
#define WW 512
#define NH 63
#define NW 63
#define NP (NH * NW)
#define WIN 16
#define STR 8
#define LDSW 520  // padded row stride (floats): 16B-aligned; 520%32=8 keeps
                  // emit ds_read_b128 at the structural 8-touch/bank minimum

typedef float f4 __attribute__((ext_vector_type(4)));

__global__ __launch_bounds__(256) void extract_patches_lds(
    const float* __restrict__ x, float* __restrict__ out) {
  __shared__ float lds[WIN * LDSW];  // 33,280 B -> 4 blocks/CU resident

  unsigned int blk = blockIdx.x;          // (b, c, ph)
  unsigned int ph = blk % NH;
  unsigned int t2 = blk / NH;
  unsigned int c  = t2 % CC;
  unsigned int b  = t2 / CC;
  unsigned int tid = threadIdx.x;

  // ---- Stage: rows [ph*8, ph*8+16) of x[b][c] — 16*512 floats, contiguous.
  const f4* src = reinterpret_cast<const f4*>(
      x + (((size_t)(b * CC + c) * HH + ph * STR) * WW));
  #pragma unroll
  for (int k = 0; k < 8; ++k) {
    unsigned int idx  = tid + k * 256u;   // float4 index within the 32 KB strip
    f4 v = src[idx];
    unsigned int row  = idx >> 7;         // 128 float4s per row
    unsigned int col4 = idx & 127u;
    *reinterpret_cast<f4*>(&lds[row * LDSW + col4 * 4u]) = v;
  }
  __syncthreads();

  // ---- Emit: wave w owns patches pw in [w*16, w*16+16); lane l owns f4 r=l.
  // Store addresses grow monotonically per wave: 1 KB contiguous per patch,
  // 3 KB stride between patches (c is the middle output dim).
  unsigned int w = tid >> 6;      // wave id 0..3
  unsigned int l = tid & 63u;     // lane
  unsigned int i  = l >> 2;       // window row
  unsigned int j4 = l & 3u;       // float4 within 16-wide window row
  const float* lrow = &lds[i * LDSW + j4 * 4u];
  f4* dst = reinterpret_cast<f4*>(out) +
            (((size_t)b * NP + (size_t)ph * NW) * CC + c) * 64u + l;
  #pragma unroll
  for (unsigned int k = 0; k < 16; ++k) {
    unsigned int pw = w * 16u + k;
    if (pw < NW) {
      f4 v = *reinterpret_cast<const f4*>(lrow + pw * STR);
      dst[(size_t)pw * (CC * 64u)] = v;
    }
  }
}

extern "C" void kernel_launch(void* const* d_in, const int* in_sizes, int n_in,
                              void* d_out, int out_size, void* d_ws, size_t ws_size,
                              hipStream_t stream) {
  const float* x = (const float*)d_in[0];
  float* out = (float*)d_out;
  dim3 grid(BB * CC * NH);  // 3024 blocks
  extract_patches_lds<<<grid, 256, 0, stream>>>(x, out);
}

// Round 7
// 228.271 us; speedup vs baseline: 1.0009x; 1.0009x over previous
//
#include <hip/hip_runtime.h>

// ExtractTensorPatches: x (16,3,512,512) f32, window 16x16, stride 8x8, pad 0.
// out (16, 63*63, 3, 16, 16) f32.
//
// Block = (b, c, ph): stage 16 input rows (contiguous 32 KB) into LDS, emit
// 63 patches (coalesced 1 KB wave stores). R7 changes vs R6:
//  - stage via __builtin_amdgcn_global_load_lds width=16 (global->LDS DMA,
//    no VGPR round-trip; m93->m97 measured 1.69x on staging-bound GEMM step)
//  - LDSW 520 -> 512: LDS image is linear (DMA-compatible trivially) and
//    LDS = 32768 B exactly -> 5 blocks/CU (was 4). Emit ds_read_b128 bank
//    touches go 8 -> 16 per instr; ~256 cyc/wave, negligible vs memory.

#define BB 16
#define CC 3
#define HH 512
#define WW 512
#define NH 63
#define NW 63
#define NP (NH * NW)
#define WIN 16
#define STR 8
#define LDSW 512

typedef float f4 __attribute__((ext_vector_type(4)));

typedef const __attribute__((address_space(1))) void gv_t;
typedef __attribute__((address_space(3))) void lv_t;

__global__ __launch_bounds__(256) void extract_patches_lds(
    const float* __restrict__ x, float* __restrict__ out) {
  __shared__ float lds[WIN * LDSW];  // 32,768 B -> 5 blocks/CU

  unsigned int blk = blockIdx.x;          // (b, c, ph)
  unsigned int ph = blk % NH;
  unsigned int t2 = blk / NH;
  unsigned int c  = t2 % CC;
  unsigned int b  = t2 / CC;
  unsigned int tid = threadIdx.x;

  // ---- Stage: rows [ph*8, ph*8+16) of x[b][c] — 16*512 floats, contiguous,
  // and the LDS image is the identical linear layout (LDSW==WW).
  // Per wave+k: lanes cover 64 consecutive float4s -> LDS dest is
  // wave-uniform base + lane*16, exactly the global_load_lds contract.
  const float* srcf = x + (((size_t)(b * CC + c) * HH + ph * STR) * WW);
  #pragma unroll
  for (int k = 0; k < 8; ++k) {
    unsigned int idx = tid + k * 256u;                 // float4 index
    gv_t* g = (gv_t*)(srcf + (size_t)idx * 4u);
    lv_t* l = (lv_t*)((char*)lds + (size_t)idx * 16u);
    __builtin_amdgcn_global_load_lds(g, l, 16, 0, 0);
  }
  __syncthreads();

  // ---- Emit: wave w owns patches pw in [w*16, w*16+16); lane l owns f4 r=l.
  // 1 KB contiguous store per wave-instruction, monotone per-wave stream.
  unsigned int w = tid >> 6;      // wave id 0..3
  unsigned int l = tid & 63u;     // lane
  unsigned int i  = l >> 2;       // window row
  unsigned int j4 = l & 3u;       // float4 within 16-wide window row
  const float* lrow = &lds[i * LDSW + j4 * 4u];
  f4* dst = reinterpret_cast<f4*>(out) +
            (((size_t)b * NP + (size_t)ph * NW) * CC + c) * 64u + l;
  #pragma unroll
  for (unsigned int k = 0; k < 16; ++k) {
    unsigned int pw = w * 16u + k;
    if (pw < NW) {
      f4 v = *reinterpret_cast<const f4*>(lrow + pw * STR);
      dst[(size_t)pw * (CC * 64u)] = v;
    }
  }
}

extern "C" void kernel_launch(void* const* d_in, const int* in_sizes, int n_in,
                              void* d_out, int out_size, void* d_ws, size_t ws_size,
                              hipStream_t stream) {
  const float* x = (const float*)d_in[0];
  float* out = (float*)d_out;
  dim3 grid(BB * CC * NH);  // 3024 blocks
  extract_patches_lds<<<grid, 256, 0, stream>>>(x, out);
}